// Round 3
// baseline (181.177 us; speedup 1.0000x reference)
//
#include <hip/hip_runtime.h>
#include <math.h>

#if defined(__has_builtin)
#  if __has_builtin(__builtin_amdgcn_exp2f)
#    define EXP2F(x) __builtin_amdgcn_exp2f(x)
#  endif
#  if __has_builtin(__builtin_amdgcn_rcpf)
#    define RCPF(x) __builtin_amdgcn_rcpf(x)
#  endif
#endif
#ifndef EXP2F
#  define EXP2F(x) exp2f(x)
#endif
#ifndef RCPF
#  define RCPF(x) (1.0f/(x))
#endif

static constexpr int Bn = 16, QN = 512, KN = 512, Hn = 64, DV = 256, DIN = 256;
static constexpr int TQ = 8;                   // R11: back to 8 q/block, 1024 blocks
static constexpr float TWO_LOG2E = 2.8853900817779268f;  // 2*log2(e)
static constexpr float LOG2E     = 1.4426950408889634f;

typedef __attribute__((ext_vector_type(8))) short short8;  // 8 bf16
typedef __attribute__((ext_vector_type(4))) float f32x4;

__device__ __forceinline__ short f2bf(float x) {          // RNE fp32->bf16
  unsigned u = __builtin_bit_cast(unsigned, x);
  u += 0x7FFF + ((u >> 16) & 1);
  return (short)(u >> 16);
}
__device__ __forceinline__ float bf2f(short h) {
  return __builtin_bit_cast(float, ((unsigned)(unsigned short)h) << 16);
}

// Projections via MFMA, 3-pass bf16 hi/lo (R7-verified numerics; R9 layout).
// Outputs TRANSPOSED [b][h][n] so attn's q-side reads are block-uniform
// (scalar s_load). Block 0 also writes wv2 = 2*wv.
__global__ __launch_bounds__(256) void proj_mfma(
    const float* __restrict__ queries, const float* __restrict__ keys,
    const float* __restrict__ Wq, const float* __restrict__ Wk,
    const float* __restrict__ wv,
    float* __restrict__ qT, float* __restrict__ ekT, float* __restrict__ wv2)
{
  __shared__ float tr[4][16][20];                // 5.1 KB transpose tiles
  int t = threadIdx.x;
  int lane = t & 63, wid = t >> 6;
  if (blockIdx.x == 0 && t < Hn) wv2[t] = 2.0f * wv[t];
  bool is_k = blockIdx.x >= 512;
  int trow = (blockIdx.x & 511) * 16;
  const float* X = is_k ? keys : queries;
  const float* W = is_k ? Wk : Wq;
  float* dT = is_k ? ekT : qT;
  int mr = lane & 15, quad = lane >> 4;
  const float* xp = X + (size_t)(trow + mr) * DIN + quad * 8;
  const float* wp = W + (size_t)(wid * 16 + mr) * DIN + quad * 8;

  f32x4 acc = (f32x4){0.f, 0.f, 0.f, 0.f};
  #pragma unroll
  for (int kc = 0; kc < 8; ++kc) {
    float4 a0 = *(const float4*)(xp + kc * 32);
    float4 a1 = *(const float4*)(xp + kc * 32 + 4);
    float4 b0 = *(const float4*)(wp + kc * 32);
    float4 b1 = *(const float4*)(wp + kc * 32 + 4);
    float av[8] = {a0.x, a0.y, a0.z, a0.w, a1.x, a1.y, a1.z, a1.w};
    float bv[8] = {b0.x, b0.y, b0.z, b0.w, b1.x, b1.y, b1.z, b1.w};
    short8 ah, al, bh, bl;
    #pragma unroll
    for (int j = 0; j < 8; ++j) {
      ah[j] = f2bf(av[j]);
      al[j] = f2bf(av[j] - bf2f(ah[j]));
      bh[j] = f2bf(bv[j]);
      bl[j] = f2bf(bv[j] - bf2f(bh[j]));
    }
    acc = __builtin_amdgcn_mfma_f32_16x16x32_bf16(al, bh, acc, 0, 0, 0);
    acc = __builtin_amdgcn_mfma_f32_16x16x32_bf16(ah, bl, acc, 0, 0, 0);
    acc = __builtin_amdgcn_mfma_f32_16x16x32_bf16(ah, bh, acc, 0, 0, 0);
  }
  // C/D: col = lane&15 (=h_local), row = quad*4 + reg (=n_local)  [verified R4-R8]
  #pragma unroll
  for (int reg = 0; reg < 4; ++reg)              // wave-private tile: no barrier
    tr[wid][mr][quad * 4 + reg] = EXP2F(acc[reg] * TWO_LOG2E);
  int b = trow >> 9, rr = trow & 511;
  #pragma unroll
  for (int hp = 0; hp < 4; ++hp) {
    int h_l = hp * 4 + quad, r_l = mr;
    dT[((size_t)b * Hn + wid * 16 + h_l) * 512 + rr + r_l] = tr[wid][h_l][r_l];
  }
}

// Fused attention — R11. Evidence: R8(occ30)/R9(occ57) both 65us, R10's
// readlane PV regressed -> bottleneck is NOT occupancy/L2-BW/LDS-count; it is
// exposed VMEM latency in PV (load->fmac chain, unroll-4) with barrier-
// lockstepped waves all stalling in the same pattern. Changes:
//  * PV: broadcast ds_read_b128 restored (free: 0 conflicts), V loads
//    software-pipelined 8 DEEP, TQ=8 -> 8 fmac per load (2x issue per load).
//  * 1024 blocks; complementary-quad rank map: co-resident slots
//    {s,s+4,s+8,s+12} get ranks {i,7-i,8+i,15-i} (const per-CU work sum).
//  * score phase: R9/R10 form (s_load q, paired rcp, ek prefetch), TQ=8.
//  All math and summation order identical to R8/R9 -> absmax unchanged.
__global__ __launch_bounds__(512) void attn_kernel(
    const float* __restrict__ qT,      // [B,64,512] exp2(C*q) transposed
    const float* __restrict__ ekT,     // [B,64,512] exp2(C*k) transposed
    const float* __restrict__ values,  // [B,512,256]
    const int*   __restrict__ valid_lens,
    const float* __restrict__ wv2,     // [64] = 2*wv
    float* __restrict__ out)           // [B,512,256]
{
  __shared__ __align__(16) float pt[KN][12];     // 24 KB  p rows (8 + pad 4)
  __shared__ __align__(16) float pacc[TQ][DV];   // 8 KB   upper-half PV partials
  __shared__ float wsum[8][TQ];
  __shared__ float inv_s[TQ];
  __shared__ int srank[Bn];

  int t = threadIdx.x;
  int lane = t & 63, wave = t >> 6;

  // ---- rank table: srank[r] = batch with r-th largest L ----
  if (t < Bn) {
    int Lb = valid_lens[t];
    int r = 0;
    #pragma unroll
    for (int b2 = 0; b2 < Bn; ++b2) {
      int L2 = valid_lens[b2];
      r += (L2 > Lb || (L2 == Lb && b2 < t)) ? 1 : 0;
    }
    srank[r] = t;
  }
  __syncthreads();

  // complementary-quad mapping: slots {i,i+4,i+8,i+12} co-reside (round-robin
  // over 256 CUs); give them ranks {i, 7-i, 8+i, 15-i} -> per-CU sum ~const.
  int slot = blockIdx.x >> 6;                    // 0..15
  int gq = slot >> 2, iq = slot & 3;
  int jr = (gq == 0) ? iq : (gq == 1) ? 7 - iq : (gq == 2) ? 8 + iq : 15 - iq;
  int b = __builtin_amdgcn_readfirstlane(srank[jr]);
  int L = __builtin_amdgcn_readfirstlane(valid_lens[b]);
  int q0 = (blockIdx.x & 63) * TQ;

  float S = 0.f;                                 // sum_h wv[h] (wv2 = 2*wv)
  #pragma unroll
  for (int h = 0; h < Hn; ++h) S += wv2[h];
  S *= 0.5f;

  // ---- scores: thread owns k = t ----
  {
    int k = t;
    float p[TQ];
    if (k < L) {
      float sc[TQ];
      #pragma unroll
      for (int r = 0; r < TQ; ++r) sc[r] = S;
      const float* kp = ekT + (size_t)b * Hn * KN + k;
      const float* qb = qT  + (size_t)b * Hn * QN + q0;
      float ekv[8];
      #pragma unroll
      for (int j = 0; j < 8; ++j)                // prologue: group 0 in flight
        ekv[j] = kp[(size_t)j * KN];
      #pragma unroll
      for (int h0 = 0; h0 < Hn; h0 += 8) {
        float ekn[8];
        if (h0 + 8 < Hn) {
          #pragma unroll
          for (int j = 0; j < 8; ++j)            // prefetch next group
            ekn[j] = kp[(size_t)(h0 + 8 + j) * KN];
        }
        #pragma unroll
        for (int jp = 0; jp < 4; ++jp) {         // paired h: 1 rcp per 2 h
          int ha = h0 + 2 * jp;
          float wa = wv2[ha], wb = wv2[ha + 1];  // uniform -> SGPR
          float4 qa0 = *(const float4*)(qb + (size_t)ha * QN);           // s_load
          float4 qa1 = *(const float4*)(qb + (size_t)ha * QN + 4);       // s_load
          float4 qc0 = *(const float4*)(qb + (size_t)(ha + 1) * QN);     // s_load
          float4 qc1 = *(const float4*)(qb + (size_t)(ha + 1) * QN + 4); // s_load
          float eka = ekv[2 * jp], ekb = ekv[2 * jp + 1];
          float da, db, num;
          da = qa0.x * eka + 1.0f; db = qc0.x * ekb + 1.0f;
          num = wa * db + wb * da; sc[0] -= num * RCPF(da * db);
          da = qa0.y * eka + 1.0f; db = qc0.y * ekb + 1.0f;
          num = wa * db + wb * da; sc[1] -= num * RCPF(da * db);
          da = qa0.z * eka + 1.0f; db = qc0.z * ekb + 1.0f;
          num = wa * db + wb * da; sc[2] -= num * RCPF(da * db);
          da = qa0.w * eka + 1.0f; db = qc0.w * ekb + 1.0f;
          num = wa * db + wb * da; sc[3] -= num * RCPF(da * db);
          da = qa1.x * eka + 1.0f; db = qc1.x * ekb + 1.0f;
          num = wa * db + wb * da; sc[4] -= num * RCPF(da * db);
          da = qa1.y * eka + 1.0f; db = qc1.y * ekb + 1.0f;
          num = wa * db + wb * da; sc[5] -= num * RCPF(da * db);
          da = qa1.z * eka + 1.0f; db = qc1.z * ekb + 1.0f;
          num = wa * db + wb * da; sc[6] -= num * RCPF(da * db);
          da = qa1.w * eka + 1.0f; db = qc1.w * ekb + 1.0f;
          num = wa * db + wb * da; sc[7] -= num * RCPF(da * db);
        }
        if (h0 + 8 < Hn) {
          #pragma unroll
          for (int j = 0; j < 8; ++j) ekv[j] = ekn[j];
        }
      }
      #pragma unroll
      for (int r = 0; r < TQ; ++r) p[r] = EXP2F(sc[r] * LOG2E);
      *(float4*)&pt[k][0] = make_float4(p[0], p[1], p[2], p[3]);
      *(float4*)&pt[k][4] = make_float4(p[4], p[5], p[6], p[7]);
    } else {
      #pragma unroll
      for (int r = 0; r < TQ; ++r) p[r] = 0.f;
    }
    #pragma unroll
    for (int r = 0; r < TQ; ++r) {               // in-register row sums
      float s = p[r];
      #pragma unroll
      for (int off = 32; off > 0; off >>= 1) s += __shfl_xor(s, off, 64);
      if (lane == r) wsum[wave][r] = s;
    }
  }
  __syncthreads();
  if (t < TQ) {
    float s = 0.f;
    #pragma unroll
    for (int w = 0; w < 8; ++w) s += wsum[w][t];
    inv_s[t] = 1.0f / s;                         // read after pacc barrier
  }

  // ---- PV: thread owns col c = t&255, half of k (t>>8), 8-deep pipeline ----
  int c = t & (DV - 1), half = t >> 8;
  int mid = L >> 1;
  int k0 = half ? mid : 0;
  int k1 = half ? L : mid;
  float acc[TQ];
  #pragma unroll
  for (int r = 0; r < TQ; ++r) acc[r] = 0.f;
  const float* vb = values + (size_t)b * KN * DV + c;
  int n8 = (k1 - k0) >> 3;
  int kb = k0;
  if (n8 > 0) {
    float vv[8];
    #pragma unroll
    for (int j = 0; j < 8; ++j) vv[j] = vb[(size_t)(k0 + j) * DV];
    for (int g = 0; g < n8 - 1; ++g) {
      int kc = k0 + g * 8;
      float vn[8];
      #pragma unroll
      for (int j = 0; j < 8; ++j)                // next 8 V rows in flight
        vn[j] = vb[(size_t)(kc + 8 + j) * DV];
      #pragma unroll
      for (int j = 0; j < 8; ++j) {
        float4 pa = *(const float4*)&pt[kc + j][0];    // LDS broadcast (free)
        float4 pb = *(const float4*)&pt[kc + j][4];
        float val = vv[j];
        acc[0] += pa.x * val; acc[1] += pa.y * val;
        acc[2] += pa.z * val; acc[3] += pa.w * val;
        acc[4] += pb.x * val; acc[5] += pb.y * val;
        acc[6] += pb.z * val; acc[7] += pb.w * val;
      }
      #pragma unroll
      for (int j = 0; j < 8; ++j) vv[j] = vn[j];
    }
    int kc = k0 + (n8 - 1) * 8;                  // last full group (no prefetch)
    #pragma unroll
    for (int j = 0; j < 8; ++j) {
      float4 pa = *(const float4*)&pt[kc + j][0];
      float4 pb = *(const float4*)&pt[kc + j][4];
      float val = vv[j];
      acc[0] += pa.x * val; acc[1] += pa.y * val;
      acc[2] += pa.z * val; acc[3] += pa.w * val;
      acc[4] += pb.x * val; acc[5] += pb.y * val;
      acc[6] += pb.z * val; acc[7] += pb.w * val;
    }
    kb = k0 + n8 * 8;
  }
  #pragma unroll 2
  for (; kb < k1; ++kb) {                        // tail < 8 iters
    float val = vb[(size_t)kb * DV];
    float4 pa = *(const float4*)&pt[kb][0];
    float4 pb = *(const float4*)&pt[kb][4];
    acc[0] += pa.x * val; acc[1] += pa.y * val;
    acc[2] += pa.z * val; acc[3] += pa.w * val;
    acc[4] += pb.x * val; acc[5] += pb.y * val;
    acc[6] += pb.z * val; acc[7] += pb.w * val;
  }
  if (half) {
    #pragma unroll
    for (int r = 0; r < TQ; ++r) pacc[r][c] = acc[r];
  }
  __syncthreads();
  if (!half) {
    float* ob = out + (size_t)(b * QN + q0) * DV + c;
    #pragma unroll
    for (int r = 0; r < TQ; ++r)
      ob[(size_t)r * DV] = (acc[r] + pacc[r][c]) * inv_s[r];
  }
}

extern "C" void kernel_launch(void* const* d_in, const int* in_sizes, int n_in,
                              void* d_out, int out_size, void* d_ws, size_t ws_size,
                              hipStream_t stream) {
  const float* queries    = (const float*)d_in[0];
  const float* keys       = (const float*)d_in[1];
  const float* values     = (const float*)d_in[2];
  const int*   valid_lens = (const int*)d_in[3];
  const float* Wq         = (const float*)d_in[4];
  const float* Wk         = (const float*)d_in[5];
  const float* wv         = (const float*)d_in[6];
  float* out = (float*)d_out;

  char* ws = (char*)d_ws;
  float* qT  = (float*)ws;                       // [B,64,512] = 2 MB
  float* ekT = qT + (size_t)Bn * Hn * QN;        // [B,64,512] = 2 MB
  float* wv2 = ekT + (size_t)Bn * Hn * KN;       // [64]

  proj_mfma<<<1024, 256, 0, stream>>>(queries, keys, Wq, Wk, wv, qT, ekT, wv2);
  attn_kernel<<<Bn * (QN / TQ), 512, 0, stream>>>(qT, ekT, values,
                                                  valid_lens, wv2, out);
}

// Round 4
// 173.872 us; speedup vs baseline: 1.0420x; 1.0420x over previous
//
#include <hip/hip_runtime.h>
#include <math.h>

#if defined(__has_builtin)
#  if __has_builtin(__builtin_amdgcn_exp2f)
#    define EXP2F(x) __builtin_amdgcn_exp2f(x)
#  endif
#  if __has_builtin(__builtin_amdgcn_rcpf)
#    define RCPF(x) __builtin_amdgcn_rcpf(x)
#  endif
#endif
#ifndef EXP2F
#  define EXP2F(x) exp2f(x)
#endif
#ifndef RCPF
#  define RCPF(x) (1.0f/(x))
#endif

static constexpr int Bn = 16, QN = 512, KN = 512, Hn = 64, DV = 256, DIN = 256;
static constexpr int TQ = 4;                   // R9 geometry: 2048 blocks, LPT
static constexpr float TWO_LOG2E = 2.8853900817779268f;  // 2*log2(e)
static constexpr float LOG2E     = 1.4426950408889634f;

typedef __attribute__((ext_vector_type(8))) short short8;  // 8 bf16
typedef __attribute__((ext_vector_type(4))) float f32x4;

__device__ __forceinline__ short f2bf(float x) {          // RNE fp32->bf16
  unsigned u = __builtin_bit_cast(unsigned, x);
  u += 0x7FFF + ((u >> 16) & 1);
  return (short)(u >> 16);
}
__device__ __forceinline__ float bf2f(short h) {
  return __builtin_bit_cast(float, ((unsigned)(unsigned short)h) << 16);
}

// Projections via MFMA, 3-pass bf16 hi/lo (R7-verified numerics; R9 layout).
// Outputs TRANSPOSED [b][h][n] so attn's q-side reads are block-uniform
// (scalar s_load). Block 0 also writes wv2 = 2*wv.
__global__ __launch_bounds__(256) void proj_mfma(
    const float* __restrict__ queries, const float* __restrict__ keys,
    const float* __restrict__ Wq, const float* __restrict__ Wk,
    const float* __restrict__ wv,
    float* __restrict__ qT, float* __restrict__ ekT, float* __restrict__ wv2)
{
  __shared__ float tr[4][16][20];                // 5.1 KB transpose tiles
  int t = threadIdx.x;
  int lane = t & 63, wid = t >> 6;
  if (blockIdx.x == 0 && t < Hn) wv2[t] = 2.0f * wv[t];
  bool is_k = blockIdx.x >= 512;
  int trow = (blockIdx.x & 511) * 16;
  const float* X = is_k ? keys : queries;
  const float* W = is_k ? Wk : Wq;
  float* dT = is_k ? ekT : qT;
  int mr = lane & 15, quad = lane >> 4;
  const float* xp = X + (size_t)(trow + mr) * DIN + quad * 8;
  const float* wp = W + (size_t)(wid * 16 + mr) * DIN + quad * 8;

  f32x4 acc = (f32x4){0.f, 0.f, 0.f, 0.f};
  #pragma unroll
  for (int kc = 0; kc < 8; ++kc) {
    float4 a0 = *(const float4*)(xp + kc * 32);
    float4 a1 = *(const float4*)(xp + kc * 32 + 4);
    float4 b0 = *(const float4*)(wp + kc * 32);
    float4 b1 = *(const float4*)(wp + kc * 32 + 4);
    float av[8] = {a0.x, a0.y, a0.z, a0.w, a1.x, a1.y, a1.z, a1.w};
    float bv[8] = {b0.x, b0.y, b0.z, b0.w, b1.x, b1.y, b1.z, b1.w};
    short8 ah, al, bh, bl;
    #pragma unroll
    for (int j = 0; j < 8; ++j) {
      ah[j] = f2bf(av[j]);
      al[j] = f2bf(av[j] - bf2f(ah[j]));
      bh[j] = f2bf(bv[j]);
      bl[j] = f2bf(bv[j] - bf2f(bh[j]));
    }
    acc = __builtin_amdgcn_mfma_f32_16x16x32_bf16(al, bh, acc, 0, 0, 0);
    acc = __builtin_amdgcn_mfma_f32_16x16x32_bf16(ah, bl, acc, 0, 0, 0);
    acc = __builtin_amdgcn_mfma_f32_16x16x32_bf16(ah, bh, acc, 0, 0, 0);
  }
  // C/D: col = lane&15 (=h_local), row = quad*4 + reg (=n_local)  [verified R4-R8]
  #pragma unroll
  for (int reg = 0; reg < 4; ++reg)              // wave-private tile: no barrier
    tr[wid][mr][quad * 4 + reg] = EXP2F(acc[reg] * TWO_LOG2E);
  int b = trow >> 9, rr = trow & 511;
  #pragma unroll
  for (int hp = 0; hp < 4; ++hp) {
    int h_l = hp * 4 + quad, r_l = mr;
    dT[((size_t)b * Hn + wid * 16 + h_l) * 512 + rr + r_l] = tr[wid][h_l][r_l];
  }
}

// Fused attention — R12. Record: R8(TQ8,occ30)=R9(TQ4,occ57)=65us though R9
// issues 2x instrs/loads -> not issue- or BW-bound; invariant is the
// per-thread latency chain (PV: 128 V-loads @ ILP4; score: 8x8 ek loads,
// no prefetch). R11's deep pipeline was right but crossed the 64-VGPR cliff
// (68 VGPR -> 2 blk/CU -> 95us). R12 = exact R9 + latency fixes only:
//  * PV: 16-deep V prefetch (4x fewer stall events), pt broadcast kept.
//  * score: one-group-ahead ek prefetch.
//  * __launch_bounds__(512,8): force <=64 VGPR, 4 blk/CU (cliff guard).
// All FP math + summation order identical to R9 -> absmax unchanged.
__global__ __launch_bounds__(512, 8) void attn_kernel(
    const float* __restrict__ qT,      // [B,64,512] exp2(C*q) transposed
    const float* __restrict__ ekT,     // [B,64,512] exp2(C*k) transposed
    const float* __restrict__ values,  // [B,512,256]
    const int*   __restrict__ valid_lens,
    const float* __restrict__ wv2,     // [64] = 2*wv
    float* __restrict__ out)           // [B,512,256]
{
  __shared__ __align__(16) float pt[KN][TQ];     // 8 KB  p rows, float4 each
  __shared__ __align__(16) float pacc[TQ][DV];   // 4 KB  upper-half PV partials
  __shared__ float wsum[8][TQ];
  __shared__ float inv_s[TQ];
  __shared__ int srank[Bn];

  int t = threadIdx.x;
  int lane = t & 63, wave = t >> 6;

  // ---- rank table: srank[r] = batch with r-th largest L ----
  if (t < Bn) {
    int Lb = valid_lens[t];
    int r = 0;
    #pragma unroll
    for (int b2 = 0; b2 < Bn; ++b2) {
      int L2 = valid_lens[b2];
      r += (L2 > Lb || (L2 == Lb && b2 < t)) ? 1 : 0;
    }
    srank[r] = t;
  }
  __syncthreads();

  int rank = blockIdx.x >> 7;                    // 0..15, L-descending (LPT)
  int b = __builtin_amdgcn_readfirstlane(srank[rank]);
  int L = __builtin_amdgcn_readfirstlane(valid_lens[b]);
  int q0 = (blockIdx.x & 127) * TQ;

  float S = 0.f;                                 // sum_h wv[h] (wv2 = 2*wv)
  #pragma unroll
  for (int h = 0; h < Hn; ++h) S += wv2[h];
  S *= 0.5f;

  // ---- scores: thread owns k = t ----
  {
    int k = t;
    float p[TQ];
    if (k < L) {
      float sc[TQ];
      #pragma unroll
      for (int r = 0; r < TQ; ++r) sc[r] = S;
      const float* kp = ekT + (size_t)b * Hn * KN + k;
      const float* qb = qT  + (size_t)b * Hn * QN + q0;
      float ekv[8];
      #pragma unroll
      for (int j = 0; j < 8; ++j)                // prologue: group 0 in flight
        ekv[j] = kp[(size_t)j * KN];
      #pragma unroll
      for (int h0 = 0; h0 < Hn; h0 += 8) {
        float ekn[8];
        if (h0 + 8 < Hn) {
          #pragma unroll
          for (int j = 0; j < 8; ++j)            // prefetch next group
            ekn[j] = kp[(size_t)(h0 + 8 + j) * KN];
        }
        #pragma unroll
        for (int jp = 0; jp < 4; ++jp) {         // paired h: 1 rcp per 2 h
          int ha = h0 + 2 * jp;
          float wa = wv2[ha], wb = wv2[ha + 1];  // uniform -> SGPR
          float4 qa = *(const float4*)(qb + (size_t)ha * QN);        // s_load
          float4 qc = *(const float4*)(qb + (size_t)(ha + 1) * QN);  // s_load
          float eka = ekv[2 * jp], ekb = ekv[2 * jp + 1];
          float da, db, num;
          da = qa.x * eka + 1.0f; db = qc.x * ekb + 1.0f;
          num = wa * db + wb * da; sc[0] -= num * RCPF(da * db);
          da = qa.y * eka + 1.0f; db = qc.y * ekb + 1.0f;
          num = wa * db + wb * da; sc[1] -= num * RCPF(da * db);
          da = qa.z * eka + 1.0f; db = qc.z * ekb + 1.0f;
          num = wa * db + wb * da; sc[2] -= num * RCPF(da * db);
          da = qa.w * eka + 1.0f; db = qc.w * ekb + 1.0f;
          num = wa * db + wb * da; sc[3] -= num * RCPF(da * db);
        }
        if (h0 + 8 < Hn) {
          #pragma unroll
          for (int j = 0; j < 8; ++j) ekv[j] = ekn[j];
        }
      }
      #pragma unroll
      for (int r = 0; r < TQ; ++r) p[r] = EXP2F(sc[r] * LOG2E);
      *(float4*)&pt[k][0] = make_float4(p[0], p[1], p[2], p[3]);
    } else {
      #pragma unroll
      for (int r = 0; r < TQ; ++r) p[r] = 0.f;
    }
    #pragma unroll
    for (int r = 0; r < TQ; ++r) {               // in-register row sums
      float s = p[r];
      #pragma unroll
      for (int off = 32; off > 0; off >>= 1) s += __shfl_xor(s, off, 64);
      if (lane == r) wsum[wave][r] = s;
    }
  }
  __syncthreads();
  if (t < TQ) {
    float s = 0.f;
    #pragma unroll
    for (int w = 0; w < 8; ++w) s += wsum[w][t];
    inv_s[t] = 1.0f / s;                         // read after pacc barrier
  }

  // ---- PV: thread owns col c = t&255, half of k (t>>8), 16-deep pipeline ----
  int c = t & (DV - 1), half = t >> 8;
  int mid = L >> 1;
  int k0 = half ? mid : 0;
  int k1 = half ? L : mid;
  float acc[TQ] = {0.f, 0.f, 0.f, 0.f};
  const float* vb = values + (size_t)b * KN * DV + c;
  int n16 = (k1 - k0) >> 4;
  if (n16 > 0) {
    float vv[16];
    #pragma unroll
    for (int j = 0; j < 16; ++j) vv[j] = vb[(size_t)(k0 + j) * DV];
    for (int g = 0; g < n16 - 1; ++g) {
      int kc = k0 + g * 16;
      float vn[16];
      #pragma unroll
      for (int j = 0; j < 16; ++j)               // next 16 V rows in flight
        vn[j] = vb[(size_t)(kc + 16 + j) * DV];
      #pragma unroll
      for (int j = 0; j < 16; ++j) {
        float4 pa = *(const float4*)&pt[kc + j][0];  // LDS broadcast (free)
        float val = vv[j];
        acc[0] += pa.x * val; acc[1] += pa.y * val;
        acc[2] += pa.z * val; acc[3] += pa.w * val;
      }
      #pragma unroll
      for (int j = 0; j < 16; ++j) vv[j] = vn[j];
    }
    int kc = k0 + (n16 - 1) * 16;                // last full group (no prefetch)
    #pragma unroll
    for (int j = 0; j < 16; ++j) {
      float4 pa = *(const float4*)&pt[kc + j][0];
      float val = vv[j];
      acc[0] += pa.x * val; acc[1] += pa.y * val;
      acc[2] += pa.z * val; acc[3] += pa.w * val;
    }
  }
  #pragma unroll 2
  for (int k = k0 + n16 * 16; k < k1; ++k) {     // tail < 16 iters
    float val = vb[(size_t)k * DV];
    float4 pa = *(const float4*)&pt[k][0];
    acc[0] += pa.x * val; acc[1] += pa.y * val;
    acc[2] += pa.z * val; acc[3] += pa.w * val;
  }
  if (half) {
    #pragma unroll
    for (int r = 0; r < TQ; ++r) pacc[r][c] = acc[r];
  }
  __syncthreads();
  if (!half) {
    float* ob = out + (size_t)(b * QN + q0) * DV + c;
    #pragma unroll
    for (int r = 0; r < TQ; ++r)
      ob[(size_t)r * DV] = (acc[r] + pacc[r][c]) * inv_s[r];
  }
}

extern "C" void kernel_launch(void* const* d_in, const int* in_sizes, int n_in,
                              void* d_out, int out_size, void* d_ws, size_t ws_size,
                              hipStream_t stream) {
  const float* queries    = (const float*)d_in[0];
  const float* keys       = (const float*)d_in[1];
  const float* values     = (const float*)d_in[2];
  const int*   valid_lens = (const int*)d_in[3];
  const float* Wq         = (const float*)d_in[4];
  const float* Wk         = (const float*)d_in[5];
  const float* wv         = (const float*)d_in[6];
  float* out = (float*)d_out;

  char* ws = (char*)d_ws;
  float* qT  = (float*)ws;                       // [B,64,512] = 2 MB
  float* ekT = qT + (size_t)Bn * Hn * QN;        // [B,64,512] = 2 MB
  float* wv2 = ekT + (size_t)Bn * Hn * KN;       // [64]

  proj_mfma<<<1024, 256, 0, stream>>>(queries, keys, Wq, Wk, wv, qT, ekT, wv2);
  attn_kernel<<<Bn * (QN / TQ), 512, 0, stream>>>(qT, ekT, values,
                                                  valid_lens, wv2, out);
}

// Round 5
// 163.422 us; speedup vs baseline: 1.1086x; 1.0639x over previous
//
#include <hip/hip_runtime.h>
#include <math.h>

#if defined(__has_builtin)
#  if __has_builtin(__builtin_amdgcn_exp2f)
#    define EXP2F(x) __builtin_amdgcn_exp2f(x)
#  endif
#  if __has_builtin(__builtin_amdgcn_rcpf)
#    define RCPF(x) __builtin_amdgcn_rcpf(x)
#  endif
#endif
#ifndef EXP2F
#  define EXP2F(x) exp2f(x)
#endif
#ifndef RCPF
#  define RCPF(x) (1.0f/(x))
#endif

static constexpr int Bn = 16, QN = 512, KN = 512, Hn = 64, DV = 256, DIN = 256;
static constexpr int TQ = 4;                   // R9 geometry: 2048 blocks, LPT
static constexpr int NSPLIT = 8;               // PV k-partitions (64 thr x 4 cols)
static constexpr float TWO_LOG2E = 2.8853900817779268f;  // 2*log2(e)
static constexpr float LOG2E     = 1.4426950408889634f;

typedef __attribute__((ext_vector_type(8))) short short8;  // 8 bf16
typedef __attribute__((ext_vector_type(4))) float f32x4;

__device__ __forceinline__ short f2bf(float x) {          // RNE fp32->bf16
  unsigned u = __builtin_bit_cast(unsigned, x);
  u += 0x7FFF + ((u >> 16) & 1);
  return (short)(u >> 16);
}
__device__ __forceinline__ float bf2f(short h) {
  return __builtin_bit_cast(float, ((unsigned)(unsigned short)h) << 16);
}
#define FMA4(a, s, v) \
  { (a).x += (s) * (v).x; (a).y += (s) * (v).y; \
    (a).z += (s) * (v).z; (a).w += (s) * (v).w; }
#define ADD4(a, v) \
  { (a).x += (v).x; (a).y += (v).y; (a).z += (v).z; (a).w += (v).w; }

// Projections via MFMA, 3-pass bf16 hi/lo (R7-verified numerics; R9 layout).
// Outputs TRANSPOSED [b][h][n] so attn's q-side reads are block-uniform
// (scalar s_load). Block 0 also writes wv2 = 2*wv.
__global__ __launch_bounds__(256) void proj_mfma(
    const float* __restrict__ queries, const float* __restrict__ keys,
    const float* __restrict__ Wq, const float* __restrict__ Wk,
    const float* __restrict__ wv,
    float* __restrict__ qT, float* __restrict__ ekT, float* __restrict__ wv2)
{
  __shared__ float tr[4][16][20];                // 5.1 KB transpose tiles
  int t = threadIdx.x;
  int lane = t & 63, wid = t >> 6;
  if (blockIdx.x == 0 && t < Hn) wv2[t] = 2.0f * wv[t];
  bool is_k = blockIdx.x >= 512;
  int trow = (blockIdx.x & 511) * 16;
  const float* X = is_k ? keys : queries;
  const float* W = is_k ? Wk : Wq;
  float* dT = is_k ? ekT : qT;
  int mr = lane & 15, quad = lane >> 4;
  const float* xp = X + (size_t)(trow + mr) * DIN + quad * 8;
  const float* wp = W + (size_t)(wid * 16 + mr) * DIN + quad * 8;

  f32x4 acc = (f32x4){0.f, 0.f, 0.f, 0.f};
  #pragma unroll
  for (int kc = 0; kc < 8; ++kc) {
    float4 a0 = *(const float4*)(xp + kc * 32);
    float4 a1 = *(const float4*)(xp + kc * 32 + 4);
    float4 b0 = *(const float4*)(wp + kc * 32);
    float4 b1 = *(const float4*)(wp + kc * 32 + 4);
    float av[8] = {a0.x, a0.y, a0.z, a0.w, a1.x, a1.y, a1.z, a1.w};
    float bv[8] = {b0.x, b0.y, b0.z, b0.w, b1.x, b1.y, b1.z, b1.w};
    short8 ah, al, bh, bl;
    #pragma unroll
    for (int j = 0; j < 8; ++j) {
      ah[j] = f2bf(av[j]);
      al[j] = f2bf(av[j] - bf2f(ah[j]));
      bh[j] = f2bf(bv[j]);
      bl[j] = f2bf(bv[j] - bf2f(bh[j]));
    }
    acc = __builtin_amdgcn_mfma_f32_16x16x32_bf16(al, bh, acc, 0, 0, 0);
    acc = __builtin_amdgcn_mfma_f32_16x16x32_bf16(ah, bl, acc, 0, 0, 0);
    acc = __builtin_amdgcn_mfma_f32_16x16x32_bf16(ah, bh, acc, 0, 0, 0);
  }
  // C/D: col = lane&15 (=h_local), row = quad*4 + reg (=n_local)  [verified R4-R8]
  #pragma unroll
  for (int reg = 0; reg < 4; ++reg)              // wave-private tile: no barrier
    tr[wid][mr][quad * 4 + reg] = EXP2F(acc[reg] * TWO_LOG2E);
  int b = trow >> 9, rr = trow & 511;
  #pragma unroll
  for (int hp = 0; hp < 4; ++hp) {
    int h_l = hp * 4 + quad, r_l = mr;
    dT[((size_t)b * Hn + wid * 16 + h_l) * 512 + rr + r_l] = tr[wid][h_l][r_l];
  }
}

// Fused attention — R13. Evidence chain: R8(occ30)=R9(occ57)=65us (2x instr,
// 2x loads, same time) -> latency-bound, not issue/BW/occupancy-bound. Three
// pipeline attempts all poisoned (R10 readlane chain, R11 VGPR cliff 68,
// R12 forced-64-VGPR spill: WRITE 8->64MB). R13 gets ILP structurally:
//  * PV: thread owns 4 COLS (float4 V-load, 16B/lane sweet spot) x 1/8 of k
//    (512 thr = 8 partitions x 64 lanes). Loads/thread 128->~32, 16 fmac per
//    load (was 4), pair-unrolled -> 2-4 loads in flight at ~+32 VGPR, no big
//    arrays, no spill. Cross-partition reduce via 28KB LDS, one barrier.
//  * pt reads wave-uniform broadcast (free), pt writes unchanged.
//  * score phase: R12 form (s_load q, paired rcp, ek group prefetch).
//  * NO launch_bounds min-waves (R12's lesson); LDS caps at 4 blk/CU.
// p values bit-identical; only PV partial-sum order changes (8-way vs 2-way).
__global__ __launch_bounds__(512) void attn_kernel(
    const float* __restrict__ qT,      // [B,64,512] exp2(C*q) transposed
    const float* __restrict__ ekT,     // [B,64,512] exp2(C*k) transposed
    const float* __restrict__ values,  // [B,512,256]
    const int*   __restrict__ valid_lens,
    const float* __restrict__ wv2,     // [64] = 2*wv
    float* __restrict__ out)           // [B,512,256]
{
  __shared__ __align__(16) float pt[KN][TQ];             // 8 KB  p rows
  __shared__ __align__(16) float pacc[NSPLIT - 1][TQ][DV]; // 28 KB partials
  __shared__ float wsum[8][TQ];
  __shared__ float inv_s[TQ];
  __shared__ int srank[Bn];

  int t = threadIdx.x;
  int lane = t & 63, wave = t >> 6;

  // ---- rank table: srank[r] = batch with r-th largest L ----
  if (t < Bn) {
    int Lb = valid_lens[t];
    int r = 0;
    #pragma unroll
    for (int b2 = 0; b2 < Bn; ++b2) {
      int L2 = valid_lens[b2];
      r += (L2 > Lb || (L2 == Lb && b2 < t)) ? 1 : 0;
    }
    srank[r] = t;
  }
  __syncthreads();

  int rank = blockIdx.x >> 7;                    // 0..15, L-descending (LPT)
  int b = __builtin_amdgcn_readfirstlane(srank[rank]);
  int L = __builtin_amdgcn_readfirstlane(valid_lens[b]);
  int q0 = (blockIdx.x & 127) * TQ;

  float S = 0.f;                                 // sum_h wv[h] (wv2 = 2*wv)
  #pragma unroll
  for (int h = 0; h < Hn; ++h) S += wv2[h];
  S *= 0.5f;

  // ---- scores: thread owns k = t ----
  {
    int k = t;
    float p[TQ];
    if (k < L) {
      float sc[TQ];
      #pragma unroll
      for (int r = 0; r < TQ; ++r) sc[r] = S;
      const float* kp = ekT + (size_t)b * Hn * KN + k;
      const float* qb = qT  + (size_t)b * Hn * QN + q0;
      float ekv[8];
      #pragma unroll
      for (int j = 0; j < 8; ++j)                // prologue: group 0 in flight
        ekv[j] = kp[(size_t)j * KN];
      #pragma unroll
      for (int h0 = 0; h0 < Hn; h0 += 8) {
        float ekn[8];
        if (h0 + 8 < Hn) {
          #pragma unroll
          for (int j = 0; j < 8; ++j)            // prefetch next group
            ekn[j] = kp[(size_t)(h0 + 8 + j) * KN];
        }
        #pragma unroll
        for (int jp = 0; jp < 4; ++jp) {         // paired h: 1 rcp per 2 h
          int ha = h0 + 2 * jp;
          float wa = wv2[ha], wb = wv2[ha + 1];  // uniform -> SGPR
          float4 qa = *(const float4*)(qb + (size_t)ha * QN);        // s_load
          float4 qc = *(const float4*)(qb + (size_t)(ha + 1) * QN);  // s_load
          float eka = ekv[2 * jp], ekb = ekv[2 * jp + 1];
          float da, db, num;
          da = qa.x * eka + 1.0f; db = qc.x * ekb + 1.0f;
          num = wa * db + wb * da; sc[0] -= num * RCPF(da * db);
          da = qa.y * eka + 1.0f; db = qc.y * ekb + 1.0f;
          num = wa * db + wb * da; sc[1] -= num * RCPF(da * db);
          da = qa.z * eka + 1.0f; db = qc.z * ekb + 1.0f;
          num = wa * db + wb * da; sc[2] -= num * RCPF(da * db);
          da = qa.w * eka + 1.0f; db = qc.w * ekb + 1.0f;
          num = wa * db + wb * da; sc[3] -= num * RCPF(da * db);
        }
        if (h0 + 8 < Hn) {
          #pragma unroll
          for (int j = 0; j < 8; ++j) ekv[j] = ekn[j];
        }
      }
      #pragma unroll
      for (int r = 0; r < TQ; ++r) p[r] = EXP2F(sc[r] * LOG2E);
      *(float4*)&pt[k][0] = make_float4(p[0], p[1], p[2], p[3]);
    } else {
      #pragma unroll
      for (int r = 0; r < TQ; ++r) p[r] = 0.f;
    }
    #pragma unroll
    for (int r = 0; r < TQ; ++r) {               // in-register row sums
      float s = p[r];
      #pragma unroll
      for (int off = 32; off > 0; off >>= 1) s += __shfl_xor(s, off, 64);
      if (lane == r) wsum[wave][r] = s;
    }
  }
  __syncthreads();
  if (t < TQ) {
    float s = 0.f;
    #pragma unroll
    for (int w = 0; w < 8; ++w) s += wsum[w][t];
    inv_s[t] = 1.0f / s;                         // read after pacc barrier
  }

  // ---- PV: wave g = t>>6 owns k-partition g; lane owns 4 cols c4 = lane*4 ----
  int g = wave;                                  // 0..7, uniform per wave
  int c4 = lane * 4;
  int klo = (L * g) >> 3, khi = (L * (g + 1)) >> 3;
  float4 a0 = {0.f,0.f,0.f,0.f}, a1 = a0, a2 = a0, a3 = a0;
  const float* vb = values + (size_t)b * KN * DV + c4;
  int k = klo;
  #pragma unroll 2
  for (; k + 2 <= khi; k += 2) {
    float4 v0 = *(const float4*)(vb + (size_t)k * DV);        // 16B coalesced
    float4 v1 = *(const float4*)(vb + (size_t)(k + 1) * DV);  // 2 in flight
    float4 p0 = *(const float4*)&pt[k][0];       // wave-uniform broadcast
    float4 p1 = *(const float4*)&pt[k + 1][0];
    FMA4(a0, p0.x, v0); FMA4(a1, p0.y, v0);
    FMA4(a2, p0.z, v0); FMA4(a3, p0.w, v0);
    FMA4(a0, p1.x, v1); FMA4(a1, p1.y, v1);
    FMA4(a2, p1.z, v1); FMA4(a3, p1.w, v1);
  }
  if (k < khi) {                                 // odd tail
    float4 v0 = *(const float4*)(vb + (size_t)k * DV);
    float4 p0 = *(const float4*)&pt[k][0];
    FMA4(a0, p0.x, v0); FMA4(a1, p0.y, v0);
    FMA4(a2, p0.z, v0); FMA4(a3, p0.w, v0);
  }
  if (g > 0) {                                   // partitions 1..7 park partials
    *(float4*)&pacc[g - 1][0][c4] = a0;
    *(float4*)&pacc[g - 1][1][c4] = a1;
    *(float4*)&pacc[g - 1][2][c4] = a2;
    *(float4*)&pacc[g - 1][3][c4] = a3;
  }
  __syncthreads();
  if (g == 0) {                                  // wave 0 reduces + writes
    #pragma unroll
    for (int gg = 0; gg < NSPLIT - 1; ++gg) {
      float4 x0 = *(const float4*)&pacc[gg][0][c4];
      float4 x1 = *(const float4*)&pacc[gg][1][c4];
      float4 x2 = *(const float4*)&pacc[gg][2][c4];
      float4 x3 = *(const float4*)&pacc[gg][3][c4];
      ADD4(a0, x0); ADD4(a1, x1); ADD4(a2, x2); ADD4(a3, x3);
    }
    float* ob = out + (size_t)(b * QN + q0) * DV + c4;
    float i0 = inv_s[0], i1 = inv_s[1], i2 = inv_s[2], i3 = inv_s[3];
    *(float4*)(ob + 0 * (size_t)DV) =
        make_float4(a0.x * i0, a0.y * i0, a0.z * i0, a0.w * i0);
    *(float4*)(ob + 1 * (size_t)DV) =
        make_float4(a1.x * i1, a1.y * i1, a1.z * i1, a1.w * i1);
    *(float4*)(ob + 2 * (size_t)DV) =
        make_float4(a2.x * i2, a2.y * i2, a2.z * i2, a2.w * i2);
    *(float4*)(ob + 3 * (size_t)DV) =
        make_float4(a3.x * i3, a3.y * i3, a3.z * i3, a3.w * i3);
  }
}

extern "C" void kernel_launch(void* const* d_in, const int* in_sizes, int n_in,
                              void* d_out, int out_size, void* d_ws, size_t ws_size,
                              hipStream_t stream) {
  const float* queries    = (const float*)d_in[0];
  const float* keys       = (const float*)d_in[1];
  const float* values     = (const float*)d_in[2];
  const int*   valid_lens = (const int*)d_in[3];
  const float* Wq         = (const float*)d_in[4];
  const float* Wk         = (const float*)d_in[5];
  const float* wv         = (const float*)d_in[6];
  float* out = (float*)d_out;

  char* ws = (char*)d_ws;
  float* qT  = (float*)ws;                       // [B,64,512] = 2 MB
  float* ekT = qT + (size_t)Bn * Hn * QN;        // [B,64,512] = 2 MB
  float* wv2 = ekT + (size_t)Bn * Hn * KN;       // [64]

  proj_mfma<<<1024, 256, 0, stream>>>(queries, keys, Wq, Wk, wv, qT, ekT, wv2);
  attn_kernel<<<Bn * (QN / TQ), 512, 0, stream>>>(qT, ekT, values,
                                                  valid_lens, wv2, out);
}

// Round 6
// 147.555 us; speedup vs baseline: 1.2279x; 1.1075x over previous
//
#include <hip/hip_runtime.h>
#include <math.h>

#if defined(__has_builtin)
#  if __has_builtin(__builtin_amdgcn_exp2f)
#    define EXP2F(x) __builtin_amdgcn_exp2f(x)
#  endif
#  if __has_builtin(__builtin_amdgcn_rcpf)
#    define RCPF(x) __builtin_amdgcn_rcpf(x)
#  endif
#endif
#ifndef EXP2F
#  define EXP2F(x) exp2f(x)
#endif
#ifndef RCPF
#  define RCPF(x) (1.0f/(x))
#endif

static constexpr int Bn = 16, QN = 512, KN = 512, Hn = 64, DV = 256, DIN = 256;
static constexpr int TQ = 4;                   // R9 geometry: 2048 blocks, LPT
static constexpr float TWO_LOG2E = 2.8853900817779268f;  // 2*log2(e)
static constexpr float LOG2E     = 1.4426950408889634f;

typedef __attribute__((ext_vector_type(8))) short short8;  // 8 bf16
typedef __attribute__((ext_vector_type(4))) float f32x4;

__device__ __forceinline__ short f2bf(float x) {          // RNE fp32->bf16
  unsigned u = __builtin_bit_cast(unsigned, x);
  u += 0x7FFF + ((u >> 16) & 1);
  return (short)(u >> 16);
}
__device__ __forceinline__ float bf2f(short h) {
  return __builtin_bit_cast(float, ((unsigned)(unsigned short)h) << 16);
}

// Projections via MFMA, 3-pass bf16 hi/lo (R7-verified numerics; R9 layout).
// Outputs TRANSPOSED [b][h][n] so attn's q-side reads are block-uniform
// (scalar s_load). Block 0 also writes wv2 = 2*wv.
__global__ __launch_bounds__(256) void proj_mfma(
    const float* __restrict__ queries, const float* __restrict__ keys,
    const float* __restrict__ Wq, const float* __restrict__ Wk,
    const float* __restrict__ wv,
    float* __restrict__ qT, float* __restrict__ ekT, float* __restrict__ wv2)
{
  __shared__ float tr[4][16][20];                // 5.1 KB transpose tiles
  int t = threadIdx.x;
  int lane = t & 63, wid = t >> 6;
  if (blockIdx.x == 0 && t < Hn) wv2[t] = 2.0f * wv[t];
  bool is_k = blockIdx.x >= 512;
  int trow = (blockIdx.x & 511) * 16;
  const float* X = is_k ? keys : queries;
  const float* W = is_k ? Wk : Wq;
  float* dT = is_k ? ekT : qT;
  int mr = lane & 15, quad = lane >> 4;
  const float* xp = X + (size_t)(trow + mr) * DIN + quad * 8;
  const float* wp = W + (size_t)(wid * 16 + mr) * DIN + quad * 8;

  f32x4 acc = (f32x4){0.f, 0.f, 0.f, 0.f};
  #pragma unroll
  for (int kc = 0; kc < 8; ++kc) {
    float4 a0 = *(const float4*)(xp + kc * 32);
    float4 a1 = *(const float4*)(xp + kc * 32 + 4);
    float4 b0 = *(const float4*)(wp + kc * 32);
    float4 b1 = *(const float4*)(wp + kc * 32 + 4);
    float av[8] = {a0.x, a0.y, a0.z, a0.w, a1.x, a1.y, a1.z, a1.w};
    float bv[8] = {b0.x, b0.y, b0.z, b0.w, b1.x, b1.y, b1.z, b1.w};
    short8 ah, al, bh, bl;
    #pragma unroll
    for (int j = 0; j < 8; ++j) {
      ah[j] = f2bf(av[j]);
      al[j] = f2bf(av[j] - bf2f(ah[j]));
      bh[j] = f2bf(bv[j]);
      bl[j] = f2bf(bv[j] - bf2f(bh[j]));
    }
    acc = __builtin_amdgcn_mfma_f32_16x16x32_bf16(al, bh, acc, 0, 0, 0);
    acc = __builtin_amdgcn_mfma_f32_16x16x32_bf16(ah, bl, acc, 0, 0, 0);
    acc = __builtin_amdgcn_mfma_f32_16x16x32_bf16(ah, bh, acc, 0, 0, 0);
  }
  // C/D: col = lane&15 (=h_local), row = quad*4 + reg (=n_local)  [verified R4-R8]
  #pragma unroll
  for (int reg = 0; reg < 4; ++reg)              // wave-private tile: no barrier
    tr[wid][mr][quad * 4 + reg] = EXP2F(acc[reg] * TWO_LOG2E);
  int b = trow >> 9, rr = trow & 511;
  #pragma unroll
  for (int hp = 0; hp < 4; ++hp) {
    int h_l = hp * 4 + quad, r_l = mr;
    dT[((size_t)b * Hn + wid * 16 + h_l) * 512 + rr + r_l] = tr[wid][h_l][r_l];
  }
}

// Fused attention — R14: CLEAN test of the PV-latency hypothesis.
// R9 verbatim (proven 65us, 32 VGPR, occ 57) with ONE change: PV inner loop
// is an 8-deep explicit double-buffer prefetch (vv/vn float[8]). Register
// budget ~50-56 VGPR (R9's 32 + 16 prefetch + addr) — below the 64 cliff
// (R11's bug), and NO launch_bounds min-waves (R12's forced-spill bug:
// WRITE_SIZE 8->64MB was scratch). Per-thread k order identical to R9 ->
// bit-identical output. If flat at ~65us with no spill, latency theory dead.
__global__ __launch_bounds__(512) void attn_kernel(
    const float* __restrict__ qT,      // [B,64,512] exp2(C*q) transposed
    const float* __restrict__ ekT,     // [B,64,512] exp2(C*k) transposed
    const float* __restrict__ values,  // [B,512,256]
    const int*   __restrict__ valid_lens,
    const float* __restrict__ wv2,     // [64] = 2*wv
    float* __restrict__ out)           // [B,512,256]
{
  __shared__ __align__(16) float pt[KN][TQ];     // 8 KB  p rows, float4 each
  __shared__ __align__(16) float pacc[TQ][DV];   // 4 KB  upper-half PV partials
  __shared__ float wsum[8][TQ];
  __shared__ float inv_s[TQ];
  __shared__ int srank[Bn];

  int t = threadIdx.x;
  int lane = t & 63, wave = t >> 6;

  // ---- rank table: srank[r] = batch with r-th largest L ----
  if (t < Bn) {
    int Lb = valid_lens[t];
    int r = 0;
    #pragma unroll
    for (int b2 = 0; b2 < Bn; ++b2) {
      int L2 = valid_lens[b2];
      r += (L2 > Lb || (L2 == Lb && b2 < t)) ? 1 : 0;
    }
    srank[r] = t;
  }
  __syncthreads();

  int rank = blockIdx.x >> 7;                    // 0..15, L-descending (LPT)
  int b = __builtin_amdgcn_readfirstlane(srank[rank]);
  int L = __builtin_amdgcn_readfirstlane(valid_lens[b]);
  int q0 = (blockIdx.x & 127) * TQ;

  float S = 0.f;                                 // sum_h wv[h] (wv2 = 2*wv)
  #pragma unroll
  for (int h = 0; h < Hn; ++h) S += wv2[h];
  S *= 0.5f;

  // ---- scores: thread owns k = t ---- (R9 verbatim)
  {
    int k = t;
    float p[TQ];
    if (k < L) {
      float sc[TQ];
      #pragma unroll
      for (int r = 0; r < TQ; ++r) sc[r] = S;
      const float* kp = ekT + (size_t)b * Hn * KN + k;
      const float* qb = qT  + (size_t)b * Hn * QN + q0;
      for (int h0 = 0; h0 < Hn; h0 += 8) {
        float ekv[8];
        #pragma unroll
        for (int j = 0; j < 8; ++j)              // 8 loads in flight
          ekv[j] = kp[(size_t)(h0 + j) * KN];
        #pragma unroll
        for (int jp = 0; jp < 4; ++jp) {         // paired h: 1 rcp per 2 h
          int ha = h0 + 2 * jp;
          float wa = wv2[ha], wb = wv2[ha + 1];  // uniform -> SGPR
          float4 qa = *(const float4*)(qb + (size_t)ha * QN);        // s_load
          float4 qc = *(const float4*)(qb + (size_t)(ha + 1) * QN);  // s_load
          float eka = ekv[2 * jp], ekb = ekv[2 * jp + 1];
          float da, db, num;
          da = qa.x * eka + 1.0f; db = qc.x * ekb + 1.0f;
          num = wa * db + wb * da; sc[0] -= num * RCPF(da * db);
          da = qa.y * eka + 1.0f; db = qc.y * ekb + 1.0f;
          num = wa * db + wb * da; sc[1] -= num * RCPF(da * db);
          da = qa.z * eka + 1.0f; db = qc.z * ekb + 1.0f;
          num = wa * db + wb * da; sc[2] -= num * RCPF(da * db);
          da = qa.w * eka + 1.0f; db = qc.w * ekb + 1.0f;
          num = wa * db + wb * da; sc[3] -= num * RCPF(da * db);
        }
      }
      #pragma unroll
      for (int r = 0; r < TQ; ++r) p[r] = EXP2F(sc[r] * LOG2E);
      *(float4*)&pt[k][0] = make_float4(p[0], p[1], p[2], p[3]);
    } else {
      #pragma unroll
      for (int r = 0; r < TQ; ++r) p[r] = 0.f;
    }
    #pragma unroll
    for (int r = 0; r < TQ; ++r) {               // in-register row sums
      float s = p[r];
      #pragma unroll
      for (int off = 32; off > 0; off >>= 1) s += __shfl_xor(s, off, 64);
      if (lane == r) wsum[wave][r] = s;
    }
  }
  __syncthreads();
  if (t < TQ) {
    float s = 0.f;
    #pragma unroll
    for (int w = 0; w < 8; ++w) s += wsum[w][t];
    inv_s[t] = 1.0f / s;                         // read after pacc barrier
  }

  // ---- PV: thread owns col c = t&255, half of k (t>>8), 8-deep pipeline ----
  int c = t & (DV - 1), half = t >> 8;
  int mid = L >> 1;
  int k0 = half ? mid : 0;
  int k1 = half ? L : mid;
  float acc[TQ] = {0.f, 0.f, 0.f, 0.f};
  const float* vb = values + (size_t)b * KN * DV + c;
  int n8 = (k1 - k0) >> 3;
  if (n8 > 0) {
    float vv[8];
    #pragma unroll
    for (int j = 0; j < 8; ++j) vv[j] = vb[(size_t)(k0 + j) * DV];
    for (int g = 0; g < n8 - 1; ++g) {
      int kc = k0 + g * 8;
      float vn[8];
      #pragma unroll
      for (int j = 0; j < 8; ++j)                // next 8 V rows in flight
        vn[j] = vb[(size_t)(kc + 8 + j) * DV];
      #pragma unroll
      for (int j = 0; j < 8; ++j) {
        float4 pa = *(const float4*)&pt[kc + j][0];  // LDS broadcast (free)
        float val = vv[j];
        acc[0] += pa.x * val; acc[1] += pa.y * val;
        acc[2] += pa.z * val; acc[3] += pa.w * val;
      }
      #pragma unroll
      for (int j = 0; j < 8; ++j) vv[j] = vn[j];
    }
    int kc = k0 + (n8 - 1) * 8;                  // last full group (no prefetch)
    #pragma unroll
    for (int j = 0; j < 8; ++j) {
      float4 pa = *(const float4*)&pt[kc + j][0];
      float val = vv[j];
      acc[0] += pa.x * val; acc[1] += pa.y * val;
      acc[2] += pa.z * val; acc[3] += pa.w * val;
    }
  }
  #pragma unroll 2
  for (int k = k0 + n8 * 8; k < k1; ++k) {       // tail < 8 iters
    float val = vb[(size_t)k * DV];
    float4 pa = *(const float4*)&pt[k][0];
    acc[0] += pa.x * val; acc[1] += pa.y * val;
    acc[2] += pa.z * val; acc[3] += pa.w * val;
  }
  if (half) {
    #pragma unroll
    for (int r = 0; r < TQ; ++r) pacc[r][c] = acc[r];
  }
  __syncthreads();
  if (!half) {
    float* ob = out + (size_t)(b * QN + q0) * DV + c;
    #pragma unroll
    for (int r = 0; r < TQ; ++r)
      ob[(size_t)r * DV] = (acc[r] + pacc[r][c]) * inv_s[r];
  }
}

extern "C" void kernel_launch(void* const* d_in, const int* in_sizes, int n_in,
                              void* d_out, int out_size, void* d_ws, size_t ws_size,
                              hipStream_t stream) {
  const float* queries    = (const float*)d_in[0];
  const float* keys       = (const float*)d_in[1];
  const float* values     = (const float*)d_in[2];
  const int*   valid_lens = (const int*)d_in[3];
  const float* Wq         = (const float*)d_in[4];
  const float* Wk         = (const float*)d_in[5];
  const float* wv         = (const float*)d_in[6];
  float* out = (float*)d_out;

  char* ws = (char*)d_ws;
  float* qT  = (float*)ws;                       // [B,64,512] = 2 MB
  float* ekT = qT + (size_t)Bn * Hn * QN;        // [B,64,512] = 2 MB
  float* wv2 = ekT + (size_t)Bn * Hn * KN;       // [64]

  proj_mfma<<<1024, 256, 0, stream>>>(queries, keys, Wq, Wk, wv, qT, ekT, wv2);
  attn_kernel<<<Bn * (QN / TQ), 512, 0, stream>>>(qT, ekT, values,
                                                  valid_lens, wv2, out);
}